// Round 13
// baseline (321.111 us; speedup 1.0000x reference)
//
#include <hip/hip_runtime.h>

constexpr int H  = 64;
constexpr int NT = 512;
constexpr int NBMAX = 512;   // max buckets (N<=131072)

#define FMA4(acc_, s_, v_) { (acc_).x += (s_)*(v_).x; (acc_).y += (s_)*(v_).y; \
                             (acc_).z += (s_)*(v_).z; (acc_).w += (s_)*(v_).w; }

// ---------------- Gram matrix of taxo_mean (+ fused weight transposes, tot zero) ----
__global__ void k_gram(const float* __restrict__ tm, float* __restrict__ G,
                       const float* __restrict__ Ww, const float* __restrict__ Wc,
                       const float* __restrict__ w2,
                       float* __restrict__ WTw, float* __restrict__ WTc,
                       float* __restrict__ WT2, int* __restrict__ tot, int NB) {
    int idx = blockIdx.x * blockDim.x + threadIdx.x;
    if (idx < 64 * 64) {              // one-time transposes (first 16 blocks)
        int j = idx >> 6, l = idx & 63;
        WTw[l * 64 + j] = Ww[idx];
        WTc[l * 64 + j] = Wc[idx];
        if (j < 32) WT2[l * 32 + j] = w2[idx & 2047];
    }
    if (idx < NB) tot[idx] = 0;       // zero bucket totals for k_phist atomics
    if (idx >= NT * NT) return;
    int a = idx >> 9, b = idx & (NT - 1);
    const float* ra = tm + a * H;
    const float* rb = tm + b * H;
    float s = 0.f;
#pragma unroll
    for (int k = 0; k < H; ++k) s += ra[k] * rb[k];
    G[idx] = s;
}

// ---------------- radix partition hist (+ fused nm build + atomic bucket totals) ----
__global__ void k_phist(const int* __restrict__ dst, int* __restrict__ histT,
                        const int* __restrict__ ncols, const int* __restrict__ cats,
                        const float* __restrict__ nvals, uint2* __restrict__ nm,
                        int* __restrict__ tot,
                        int NB, int NPB, int CH, int E, int N) {
    __shared__ int hist[NBMAX];
    int b = blockIdx.x, t = threadIdx.x;
    int gid = b * 256 + t;          // NPB*256 >= N
    if (gid < N) {
        int j = ncols[gid];
        nm[gid] = make_uint2(__float_as_uint(nvals[gid]),
                             (unsigned)(cats[j * 2] | (cats[j * 2 + 1] << 16)));
    }
    for (int i = t; i < NB; i += 256) hist[i] = 0;
    __syncthreads();
    int e0 = b * CH, e1 = min(E, e0 + CH);
    for (int e = e0 + t; e < e1; e += 256)
        atomicAdd(&hist[dst[e] >> 8], 1);
    __syncthreads();
    for (int i = t; i < NB; i += 256) {
        int v = hist[i];
        histT[i * NPB + b] = v;
        if (v) atomicAdd(&tot[i], v);   // bucket totals (replaces k_btot)
    }
}

__global__ void k_bscan(const int* __restrict__ tot, int* __restrict__ bbase,
                        int* __restrict__ row_start, int NB, int N, int E) {
    __shared__ int sh[NBMAX];
    int t = threadIdx.x;
    int v = (t < NB) ? tot[t] : 0;
    sh[t] = v;
    __syncthreads();
    for (int o = 1; o < NBMAX; o <<= 1) {
        int x = (t >= o) ? sh[t - o] : 0;
        __syncthreads();
        sh[t] += x;
        __syncthreads();
    }
    if (t < NB) bbase[t] = sh[t] - v;
    if (t == 0) { bbase[NB] = E; row_start[N] = E; }
}

__global__ void k_boff(const int* __restrict__ histT, const int* __restrict__ bbase,
                       int* __restrict__ boff, int NPB) {
    __shared__ int sh[NBMAX];
    int bk = blockIdx.x, t = threadIdx.x;
    int v = (t < NPB) ? histT[bk * NPB + t] : 0;
    sh[t] = v;
    __syncthreads();
    for (int o = 1; o < NBMAX; o <<= 1) {
        int x = (t >= o) ? sh[t - o] : 0;
        __syncthreads();
        sh[t] += x;
        __syncthreads();
    }
    if (t < NPB) boff[bk * NPB + t] = bbase[bk] + sh[t] - v;
}

// packed record: src (24 bits) | (dst&255)<<24  — N < 2^24
__global__ void k_part(const int* __restrict__ src, const int* __restrict__ dst,
                       const int* __restrict__ boff, unsigned* __restrict__ brec,
                       int NB, int NPB, int CH, int E) {
    __shared__ int cur[NBMAX];
    int b = blockIdx.x, t = threadIdx.x;
    for (int i = t; i < NB; i += 256) cur[i] = boff[i * NPB + b];
    __syncthreads();
    int e0 = b * CH, e1 = min(E, e0 + CH);
    for (int e = e0 + t; e < e1; e += 256) {
        int s = src[e], d = dst[e];
        int pos = atomicAdd(&cur[d >> 8], 1);
        brec[pos] = (unsigned)s | ((unsigned)(d & 255) << 24);
    }
}

// one block per bucket: LDS degree count -> scan -> row_start; CSR window fill;
// fused wt (Gram trick) -> packed se = {src, exp(wt)}, LDS sumt.
__global__ void k_csr(const unsigned* __restrict__ brec, const int* __restrict__ bbase,
                      const uint2* __restrict__ nm, const float* __restrict__ G,
                      int* __restrict__ row_start, uint2* __restrict__ se,
                      float* __restrict__ sumt, int N) {
    __shared__ int   sdeg[256];
    __shared__ int   scur[256];
    __shared__ float ssum[256];
    __shared__ float snv[256];
    __shared__ int   scc[256];
    int b = blockIdx.x, t = threadIdx.x;
    int node0 = b << 8;
    int ebase = bbase[b], eend = bbase[b + 1];
    sdeg[t] = 0; scur[t] = 0; ssum[t] = 0.f;
    int n = node0 + t;
    if (n < N) { uint2 m = nm[n]; snv[t] = __uint_as_float(m.x); scc[t] = (int)m.y; }
    __syncthreads();
    for (int i = ebase + t; i < eend; i += 256)
        atomicAdd(&sdeg[brec[i] >> 24], 1);
    __syncthreads();
    int val = sdeg[t];
    for (int o = 1; o < 256; o <<= 1) {
        int x = (t >= o) ? sdeg[t - o] : 0;
        __syncthreads();
        sdeg[t] += x;
        __syncthreads();
    }
    int gstart = ebase + sdeg[t] - val;
    if (n < N) row_start[n] = gstart;
    sdeg[t] = gstart;
    __syncthreads();
    for (int i = ebase + t; i < eend; i += 256) {
        unsigned r = brec[i];
        int s = (int)(r & 0xFFFFFFu);
        int j = (int)(r >> 24);
        int c = atomicAdd(&scur[j], 1);
        int k = sdeg[j] + c;
        uint2 ms = nm[s];
        float nvs = __uint_as_float(ms.x);
        int cs = (int)ms.y;
        int cd = scc[j];
        float wt = nvs * snv[j] *
                   (G[(cs & 0xffff) * NT + (cd & 0xffff)] + G[(cs >> 16) * NT + (cd >> 16)]);
        float ev = __expf(wt);
        se[k] = make_uint2((unsigned)s, __float_as_uint(ev));
        atomicAdd(&ssum[j], ev);
    }
    __syncthreads();
    if (n < N) sumt[n] = ssum[t];
}

// ---------------- FUSED gather-aggregate + 64x64 transform ------------------------
// One 16-lane group per node. Phase 1: owner-lane gather with packed se (1x8B load).
// Phase 2: z staged to xs with XOR swizzle -> 0 conflicts (verified r8); WF staged
// linearly from pre-transposed WT. LDS = 20480 B -> 8 blocks/CU for BOTH layers.
// EMBH: after phase 2, WF is dead -> overlay W2S into WF (8KB linear copy) behind a
// barrier; epilogue = 16 lanes x 2 cols from swizzled xs (conflict-free, r8-verified).
#define LDH(S) (*reinterpret_cast<const float4*>(h_in + (size_t)(S) * H + f))
template <bool PRELU, bool SUV, bool EMBH>
__global__ void __launch_bounds__(256, 8)
k_aggt(const float* __restrict__ h_in, const uint2* __restrict__ se,
       const int* __restrict__ row_start,
       const float* __restrict__ sumt, const float* __restrict__ s_u,
       const float* __restrict__ s_v,
       const float* __restrict__ WT, const float* __restrict__ b,
       const float* __restrict__ a_ptr, const float* __restrict__ wh,
       float* __restrict__ s_u_o, float* __restrict__ s_v_o,
       const float* __restrict__ WT2, const float* __restrict__ b2,
       float* __restrict__ emb_out,
       float* __restrict__ out, int N) {
    __shared__ float WF[64 * 64];     // phase2: W^T ; EMBH epilogue: overlaid w2^T
    __shared__ float xs[4][256];      // per-wave, XOR-swizzled
    int t = threadIdx.x;
    for (int i = t; i < 64 * 64; i += 256) WF[i] = WT[i];
    __syncthreads();                  // no divergent exit before barriers (n<N predicated)
    int sg = t >> 4, l16 = t & 15, f = l16 * 4;
    int wid = t >> 6, g = sg & 3;
    int gsw = g << 2;                 // XOR swizzle key (word units)
    int n = blockIdx.x * 16 + sg;

    // ---- phase 1: gather-aggregate (owner-lane loop, packed se) ----
    float4 z = make_float4(0.f, 0.f, 0.f, 0.f);
    if (n < N) {
        int kb = row_start[n], ke = row_start[n + 1];
        if (ke > kb) {
            float sv = s_v[n];
            float invt = 0.5f / sumt[n];
            float ssf = 0.f;
            float4 zf0 = z, zf1 = z, zt0 = z, zt1 = z;
            for (int k0 = kb; k0 < ke; k0 += 16) {
                int cnt = ke - k0; cnt = cnt < 16 ? cnt : 16;
                int cl = cnt - 1;
                int myk = k0 + (l16 <= cl ? l16 : cl);
                uint2 p = se[myk];
                int ms = (int)p.x;
                float me = __uint_as_float(p.y) * invt;
                float mw = s_u[ms] + sv;
                mw = mw >= 0.f ? mw : 0.01f * mw;
                float mf = __expf(mw);
                if (l16 > cl) { mf = 0.f; me = 0.f; }
                ssf += mf;
                for (int j0 = 0; j0 < cnt; j0 += 4) {
                    int jB = min(j0 + 1, cl), jC = min(j0 + 2, cl), jD = min(j0 + 3, cl);
                    int sA = __shfl(ms, j0, 16), sB = __shfl(ms, jB, 16);
                    int sC = __shfl(ms, jC, 16), sD = __shfl(ms, jD, 16);
                    float tfA = __shfl(mf, j0, 16), tfB = __shfl(mf, jB, 16);
                    float tfC = __shfl(mf, jC, 16), tfD = __shfl(mf, jD, 16);
                    float teA = __shfl(me, j0, 16), teB = __shfl(me, jB, 16);
                    float teC = __shfl(me, jC, 16), teD = __shfl(me, jD, 16);
                    float fB = (j0 + 1 <= cl) ? tfB : 0.f;
                    float fC = (j0 + 2 <= cl) ? tfC : 0.f;
                    float fD = (j0 + 3 <= cl) ? tfD : 0.f;
                    float eB = (j0 + 1 <= cl) ? teB : 0.f;
                    float eC = (j0 + 2 <= cl) ? teC : 0.f;
                    float eD = (j0 + 3 <= cl) ? teD : 0.f;
                    const float4 hA = LDH(sA);
                    const float4 hB = LDH(sB);
                    const float4 hC = LDH(sC);
                    const float4 hD = LDH(sD);
                    FMA4(zf0, tfA, hA); FMA4(zt0, teA, hA);
                    FMA4(zf1, fB, hB);  FMA4(zt1, eB, hB);
                    FMA4(zf0, fC, hC);  FMA4(zt0, eC, hC);
                    FMA4(zf1, fD, hD);  FMA4(zt1, eD, hD);
                }
            }
            ssf += __shfl_xor(ssf, 1); ssf += __shfl_xor(ssf, 2);
            ssf += __shfl_xor(ssf, 4); ssf += __shfl_xor(ssf, 8);
            float invf = 0.5f / ssf;
            z.x = (zf0.x + zf1.x) * invf + (zt0.x + zt1.x);
            z.y = (zf0.y + zf1.y) * invf + (zt0.y + zt1.y);
            z.z = (zf0.z + zf1.z) * invf + (zt0.z + zt1.z);
            z.w = (zf0.w + zf1.w) * invf + (zt0.w + zt1.w);
        }
    }

    // ---- phase 2: transform via swizzled xs + WF GEMV ----
    *reinterpret_cast<float4*>(&xs[wid][(g << 6) | (f ^ gsw)]) = z;
    float a = PRELU ? a_ptr[0] : 0.f;
    float4 acc = *reinterpret_cast<const float4*>(b + f);
#pragma unroll 2
    for (int l0 = 0; l0 < 64; l0 += 4) {
        const float* wp = &WF[l0 * 64 + f];
        float4 wv0 = *reinterpret_cast<const float4*>(wp);
        float4 wv1 = *reinterpret_cast<const float4*>(wp + 64);
        float4 wv2 = *reinterpret_cast<const float4*>(wp + 128);
        float4 wv3 = *reinterpret_cast<const float4*>(wp + 192);
        float4 x4 = *reinterpret_cast<const float4*>(&xs[wid][(g << 6) | (l0 ^ gsw)]);
        FMA4(acc, x4.x, wv0); FMA4(acc, x4.y, wv1);
        FMA4(acc, x4.z, wv2); FMA4(acc, x4.w, wv3);
    }
    if constexpr (PRELU) {
        acc.x = acc.x >= 0.f ? acc.x : a * acc.x;
        acc.y = acc.y >= 0.f ? acc.y : a * acc.y;
        acc.z = acc.z >= 0.f ? acc.z : a * acc.z;
        acc.w = acc.w >= 0.f ? acc.w : a * acc.w;
    }
    if (n < N) *reinterpret_cast<float4*>(out + (size_t)n * H + f) = acc;
    if constexpr (SUV) {
        float4 wu = *reinterpret_cast<const float4*>(wh + f);
        float4 wv = *reinterpret_cast<const float4*>(wh + H + f);
        float u = acc.x * wu.x + acc.y * wu.y + acc.z * wu.z + acc.w * wu.w;
        float v = acc.x * wv.x + acc.y * wv.y + acc.z * wv.z + acc.w * wv.w;
        u += __shfl_xor(u, 1); v += __shfl_xor(v, 1);
        u += __shfl_xor(u, 2); v += __shfl_xor(v, 2);
        u += __shfl_xor(u, 4); v += __shfl_xor(v, 4);
        u += __shfl_xor(u, 8); v += __shfl_xor(v, 8);
        if (l16 == 0 && n < N) { s_u_o[n] = u; s_v_o[n] = v; }
    }
    if constexpr (EMBH) {
        // acc row into this wave's xs slot (wave-local: own reads completed above)
        *reinterpret_cast<float4*>(&xs[wid][(g << 6) | (f ^ gsw)]) = acc;
        __syncthreads();                     // all waves done reading WF
        for (int i = t; i < 64 * 32; i += 256) WF[i] = WT2[i];   // overlay w2^T
        __syncthreads();
        int c0 = 2 * l16;
        float2 bb2 = *reinterpret_cast<const float2*>(b2 + c0);
        float e0 = bb2.x, e1 = bb2.y;
#pragma unroll 2
        for (int l0 = 0; l0 < 64; l0 += 4) {
            float4 x4 = *reinterpret_cast<const float4*>(&xs[wid][(g << 6) | (l0 ^ gsw)]);
            const float* wp = &WF[l0 * 32 + c0];
            float2 w0v = *reinterpret_cast<const float2*>(wp);
            float2 w1v = *reinterpret_cast<const float2*>(wp + 32);
            float2 w2v = *reinterpret_cast<const float2*>(wp + 64);
            float2 w3v = *reinterpret_cast<const float2*>(wp + 96);
            e0 += x4.x * w0v.x + x4.y * w1v.x + x4.z * w2v.x + x4.w * w3v.x;
            e1 += x4.x * w0v.y + x4.y * w1v.y + x4.z * w2v.y + x4.w * w3v.y;
        }
        float sq = e0 * e0 + e1 * e1;
        sq += __shfl_xor(sq, 1);
        sq += __shfl_xor(sq, 2);
        sq += __shfl_xor(sq, 4);
        sq += __shfl_xor(sq, 8);
        float invn = 1.f / fmaxf(sqrtf(sq), 1e-12f);
        if (n < N) {
            *reinterpret_cast<float2*>(emb_out + (size_t)n * 96 + c0) =
                make_float2(e0 * invn, e1 * invn);
        }
    }
}

// ---------------- register-tiled 64x64 transform, 8 nodes per wave (layer 0) --------
template <bool PRELU, bool SUV>
__global__ void __launch_bounds__(256, 4)
k_trans(const float* __restrict__ in, const float* __restrict__ WT,
        const float* __restrict__ b, const float* __restrict__ a_ptr,
        const float* __restrict__ wh,
        float* __restrict__ s_u_o, float* __restrict__ s_v_o,
        float* __restrict__ out, int N) {
    __shared__ float WF[64 * 64];     // WF[l*64+j] = W[j][l]
    __shared__ float xs[4][8][68];    // [wave][node-slot][l]
    int t = threadIdx.x;
    for (int i = t; i < 64 * 64; i += 256) WF[i] = WT[i];
    __syncthreads();
    int wid = t >> 6, lane = t & 63;
    int g = lane >> 4, f = lane & 15;
    float a = PRELU ? a_ptr[0] : 0.f;
    float4 bias = *reinterpret_cast<const float4*>(b + 4 * f);
    int n0 = blockIdx.x * 32 + wid * 8 + g;
    int n1 = n0 + 4;
    float4 xv0 = make_float4(0.f, 0.f, 0.f, 0.f), xv1 = xv0;
    if (n0 < N) xv0 = *reinterpret_cast<const float4*>(in + (size_t)n0 * H + 4 * f);
    if (n1 < N) xv1 = *reinterpret_cast<const float4*>(in + (size_t)n1 * H + 4 * f);
    *reinterpret_cast<float4*>(&xs[wid][g][4 * f])     = xv0;
    *reinterpret_cast<float4*>(&xs[wid][4 + g][4 * f]) = xv1;
    float4 accP = make_float4(0.f, 0.f, 0.f, 0.f), accQ = accP;
#pragma unroll 2
    for (int l0 = 0; l0 < 64; l0 += 4) {
        const float* wp = &WF[l0 * 64 + 4 * f];
        float4 wv0 = *reinterpret_cast<const float4*>(wp);
        float4 wv1 = *reinterpret_cast<const float4*>(wp + 64);
        float4 wv2 = *reinterpret_cast<const float4*>(wp + 128);
        float4 wv3 = *reinterpret_cast<const float4*>(wp + 192);
        float4 xP = *reinterpret_cast<const float4*>(&xs[wid][g][l0]);
        float4 xQ = *reinterpret_cast<const float4*>(&xs[wid][4 + g][l0]);
        FMA4(accP, xP.x, wv0); FMA4(accP, xP.y, wv1);
        FMA4(accP, xP.z, wv2); FMA4(accP, xP.w, wv3);
        FMA4(accQ, xQ.x, wv0); FMA4(accQ, xQ.y, wv1);
        FMA4(accQ, xQ.z, wv2); FMA4(accQ, xQ.w, wv3);
    }
    auto epi = [&](float4 acc, int n) {
        acc.x += bias.x; acc.y += bias.y; acc.z += bias.z; acc.w += bias.w;
        if constexpr (PRELU) {
            acc.x = acc.x >= 0.f ? acc.x : a * acc.x;
            acc.y = acc.y >= 0.f ? acc.y : a * acc.y;
            acc.z = acc.z >= 0.f ? acc.z : a * acc.z;
            acc.w = acc.w >= 0.f ? acc.w : a * acc.w;
        }
        if (n < N) *reinterpret_cast<float4*>(out + (size_t)n * H + 4 * f) = acc;
        if constexpr (SUV) {
            float4 wu = *reinterpret_cast<const float4*>(wh + 4 * f);
            float4 wv = *reinterpret_cast<const float4*>(wh + H + 4 * f);
            float u = acc.x * wu.x + acc.y * wu.y + acc.z * wu.z + acc.w * wu.w;
            float v = acc.x * wv.x + acc.y * wv.y + acc.z * wv.z + acc.w * wv.w;
            u += __shfl_xor(u, 1); v += __shfl_xor(v, 1);
            u += __shfl_xor(u, 2); v += __shfl_xor(v, 2);
            u += __shfl_xor(u, 4); v += __shfl_xor(v, 4);
            u += __shfl_xor(u, 8); v += __shfl_xor(v, 8);
            if (f == 0 && n < N) { s_u_o[n] = u; s_v_o[n] = v; }
        }
    };
    epi(accP, n0);
    epi(accQ, n1);
}

// ---------------- post stage 1: hrev gather + Psi GEMV + both cur_i, 8 nodes/wave ----
__global__ void __launch_bounds__(256, 4)
k_post1(const float* __restrict__ raw, const int* __restrict__ icols,
        const float* __restrict__ ivals, const float* __restrict__ Psi,
        const float* __restrict__ psib, const int* __restrict__ cats,
        const float* __restrict__ tm, const float* __restrict__ tsl,
        float* __restrict__ cur0, float* __restrict__ cur1, int N) {
    __shared__ float PF[64 * 68];     // PF[l*68+j] = Psi[l][j]
    __shared__ float xs[4][8][68];
    int t = threadIdx.x;
    for (int i = t; i < 64 * 64; i += 256) { int l = i >> 6, j = i & 63; PF[l * 68 + j] = Psi[i]; }
    __syncthreads();
    int wid = t >> 6, lane = t & 63;
    int g = lane >> 4, f = lane & 15;
    float pb = psib[0];
    int n0 = blockIdx.x * 32 + wid * 8 + g;
    int n1 = n0 + 4;
    float4 hr0 = make_float4(0.f, 0.f, 0.f, 0.f), hr1 = hr0;
    if (n0 < N) {
        int c = icols[n0]; float iv = ivals[n0];
        float4 rv = *reinterpret_cast<const float4*>(raw + (size_t)c * H + 4 * f);
        hr0.x = iv * rv.x; hr0.y = iv * rv.y; hr0.z = iv * rv.z; hr0.w = iv * rv.w;
    }
    if (n1 < N) {
        int c = icols[n1]; float iv = ivals[n1];
        float4 rv = *reinterpret_cast<const float4*>(raw + (size_t)c * H + 4 * f);
        hr1.x = iv * rv.x; hr1.y = iv * rv.y; hr1.z = iv * rv.z; hr1.w = iv * rv.w;
    }
    *reinterpret_cast<float4*>(&xs[wid][g][4 * f])     = hr0;
    *reinterpret_cast<float4*>(&xs[wid][4 + g][4 * f]) = hr1;
    float4 v0 = make_float4(0.f, 0.f, 0.f, 0.f), v1 = v0;
#pragma unroll 2
    for (int l0 = 0; l0 < 64; l0 += 4) {
        const float* pp = &PF[l0 * 68 + 4 * f];
        float4 pv0 = *reinterpret_cast<const float4*>(pp);
        float4 pv1 = *reinterpret_cast<const float4*>(pp + 68);
        float4 pv2 = *reinterpret_cast<const float4*>(pp + 136);
        float4 pv3 = *reinterpret_cast<const float4*>(pp + 204);
        float4 xP = *reinterpret_cast<const float4*>(&xs[wid][g][l0]);
        float4 xQ = *reinterpret_cast<const float4*>(&xs[wid][4 + g][l0]);
        FMA4(v0, xP.x, pv0); FMA4(v0, xP.y, pv1); FMA4(v0, xP.z, pv2); FMA4(v0, xP.w, pv3);
        FMA4(v1, xQ.x, pv0); FMA4(v1, xQ.y, pv1); FMA4(v1, xQ.z, pv2); FMA4(v1, xQ.w, pv3);
    }
    auto epi = [&](float4 v, float4 hr, int n) {
        if (n >= N) return;
#pragma unroll
        for (int i2 = 0; i2 < 2; ++i2) {
            int c = cats[n * 2 + i2];
            float4 m4 = *reinterpret_cast<const float4*>(tm + (size_t)c * H + 4 * f);
            float sd = v.x * m4.x + v.y * m4.y + v.z * m4.z + v.w * m4.w;
            sd += __shfl_xor(sd, 1);
            sd += __shfl_xor(sd, 2);
            sd += __shfl_xor(sd, 4);
            sd += __shfl_xor(sd, 8);
            float sig = 1.f / (1.f + __expf(-(sd + pb)));
            float4 t4 = *reinterpret_cast<const float4*>(tsl + (size_t)c * H + 4 * f);
            float4 tau, cv;
            tau.x = sig * __expf(-__expf(t4.x));
            tau.y = sig * __expf(-__expf(t4.y));
            tau.z = sig * __expf(-__expf(t4.z));
            tau.w = sig * __expf(-__expf(t4.w));
            cv.x = (1.f - tau.x) * hr.x + tau.x * m4.x;
            cv.y = (1.f - tau.y) * hr.y + tau.y * m4.y;
            cv.z = (1.f - tau.z) * hr.z + tau.z * m4.z;
            cv.w = (1.f - tau.w) * hr.w + tau.w * m4.w;
            *reinterpret_cast<float4*>((i2 ? cur1 : cur0) + (size_t)n * H + 4 * f) = cv;
        }
    };
    epi(v0, hr0, n0);
    epi(v1, hr1, n1);
}

// ---------------- post stage 2: gather cur rows, combined 64-col GEMV, normalize --------
__global__ void __launch_bounds__(256, 4)
k_post2(const float* __restrict__ cur0, const float* __restrict__ cur1,
        const int* __restrict__ ncols, const float* __restrict__ nvals,
        const float* __restrict__ w0, const float* __restrict__ b0,
        const float* __restrict__ w1, const float* __restrict__ b1,
        float* __restrict__ emb_out, int N) {
    __shared__ float WC[64 * 68];     // cols 0..31: w0^T, 32..63: w1^T
    __shared__ float xs[4][4][2][68];
    int t = threadIdx.x;
    for (int i = t; i < 64 * 64; i += 256) {
        int j = i >> 6, l = i & 63;
        WC[l * 68 + j] = (j < 32) ? w0[j * 64 + l] : w1[(j - 32) * 64 + l];
    }
    __syncthreads();
    int wid = t >> 6, lane = t & 63;
    int g = lane >> 4, f = lane & 15;
    int half = f >> 3;
    const float* bb = half ? b1 : b0;
    float4 bias = *reinterpret_cast<const float4*>(bb + 4 * (f & 7));
    for (int it = 0; it < 2; ++it) {
        int n = blockIdx.x * 32 + wid * 8 + it * 4 + g;
        float4 x0 = make_float4(0.f, 0.f, 0.f, 0.f), x1 = x0;
        if (n < N) {
            int c = ncols[n];
            float gsc = nvals[n];
            float4 c0v = *reinterpret_cast<const float4*>(cur0 + (size_t)c * H + 4 * f);
            float4 c1v = *reinterpret_cast<const float4*>(cur1 + (size_t)c * H + 4 * f);
            x0.x = gsc * c0v.x; x0.y = gsc * c0v.y; x0.z = gsc * c0v.z; x0.w = gsc * c0v.w;
            x1.x = gsc * c1v.x; x1.y = gsc * c1v.y; x1.z = gsc * c1v.z; x1.w = gsc * c1v.w;
        }
        *reinterpret_cast<float4*>(&xs[wid][g][0][4 * f]) = x0;
        *reinterpret_cast<float4*>(&xs[wid][g][1][4 * f]) = x1;
        float4 acc = bias;
#pragma unroll 4
        for (int l0 = 0; l0 < 64; l0 += 4) {
            float4 x4  = *reinterpret_cast<const float4*>(&xs[wid][g][half][l0]);
            float4 wv0 = *reinterpret_cast<const float4*>(&WC[(l0 + 0) * 68 + 4 * f]);
            float4 wv1 = *reinterpret_cast<const float4*>(&WC[(l0 + 1) * 68 + 4 * f]);
            float4 wv2 = *reinterpret_cast<const float4*>(&WC[(l0 + 2) * 68 + 4 * f]);
            float4 wv3 = *reinterpret_cast<const float4*>(&WC[(l0 + 3) * 68 + 4 * f]);
            FMA4(acc, x4.x, wv0); FMA4(acc, x4.y, wv1);
            FMA4(acc, x4.z, wv2); FMA4(acc, x4.w, wv3);
        }
        float sq = acc.x * acc.x + acc.y * acc.y + acc.z * acc.z + acc.w * acc.w;
        sq += __shfl_xor(sq, 1);
        sq += __shfl_xor(sq, 2);
        sq += __shfl_xor(sq, 4);
        float invn = 1.f / fmaxf(sqrtf(sq), 1e-12f);
        if (n < N) {
            int jb = (f & 7) * 4;
            float* o = emb_out + (size_t)n * 96 + 32 + half;
            o[2 * (jb + 0)] = acc.x * invn;
            o[2 * (jb + 1)] = acc.y * invn;
            o[2 * (jb + 2)] = acc.z * invn;
            o[2 * (jb + 3)] = acc.w * invn;
        }
    }
}

extern "C" void kernel_launch(void* const* d_in, const int* in_sizes, int n_in,
                              void* d_out, int out_size, void* d_ws, size_t ws_size,
                              hipStream_t stream) {
    const float* h      = (const float*)d_in[0];
    const int*   src    = (const int*)d_in[1];
    const int*   dst    = (const int*)d_in[2];
    const int*   cats   = (const int*)d_in[3];
    const int*   icols  = (const int*)d_in[5];
    const float* ivals  = (const float*)d_in[6];
    const int*   ncols  = (const int*)d_in[8];
    const float* nvals  = (const float*)d_in[9];
    const float* W_w    = (const float*)d_in[10];
    const float* W_b    = (const float*)d_in[11];
    const float* pre_a  = (const float*)d_in[12];
    const float* tm     = (const float*)d_in[13];
    const float* tsl    = (const float*)d_in[14];
    const float* wh     = (const float*)d_in[15];
    const float* cWw    = (const float*)d_in[16];
    const float* cWb    = (const float*)d_in[17];
    const float* psiW   = (const float*)d_in[18];
    const float* psib   = (const float*)d_in[19];
    const float* w0     = (const float*)d_in[20];
    const float* b0     = (const float*)d_in[21];
    const float* w1     = (const float*)d_in[22];
    const float* b1     = (const float*)d_in[23];
    const float* w2     = (const float*)d_in[24];
    const float* b2     = (const float*)d_in[25];

    const int N = in_sizes[0] / H;   // 100000
    const int E = in_sizes[1];       // 1600000
    const int NB = (N + 255) >> 8;   // 391 buckets
    const int NPB = NB;
    const int CH = (E + NPB - 1) / NPB;

    char* ws = (char*)d_ws;
    size_t off = 0;
    auto alloc = [&](size_t bytes) -> void* {
        void* p = ws + off;
        off = (off + bytes + 255) & ~(size_t)255;
        return p;
    };
    float*    A        = (float*)   alloc((size_t)N * H * 4);   // h1; later cur0
    float*    B        = (float*)   alloc((size_t)N * H * 4);   // h2; later cur1
    uint2*    se       = (uint2*)   alloc((size_t)E * 8);       // packed {src, et}
    unsigned* brec     = (unsigned*)alloc((size_t)E * 4);
    uint2*    nm       = (uint2*)   alloc((size_t)N * 8);
    int*      row_start= (int*)     alloc((size_t)(N + 1) * 4);
    float*    sumt     = (float*)   alloc((size_t)N * 4);
    float*    s_u0     = (float*)   alloc((size_t)N * 4);
    float*    s_v0     = (float*)   alloc((size_t)N * 4);
    float*    s_u1     = (float*)   alloc((size_t)N * 4);
    float*    s_v1     = (float*)   alloc((size_t)N * 4);
    float*    G        = (float*)   alloc((size_t)NT * NT * 4);
    int*      histT    = (int*)     alloc((size_t)NB * NPB * 4);
    int*      boff     = (int*)     alloc((size_t)NB * NPB * 4);
    int*      tot      = (int*)     alloc((size_t)NB * 4);
    int*      bbase    = (int*)     alloc((size_t)(NB + 1) * 4);
    float*    WTw      = (float*)   alloc(64 * 64 * 4);
    float*    WTc      = (float*)   alloc(64 * 64 * 4);
    float*    WT2      = (float*)   alloc(64 * 32 * 4);
    (void)ws_size; (void)n_in; (void)out_size;

    float* rawOut  = (float*)d_out;                     // N*H
    float* emb_out = (float*)d_out + (size_t)N * H;     // N*96

    dim3 b256(256);
    int nb16 = (N + 15) / 16;
    int nb32 = (N + 31) / 32;

    k_gram<<<(NT * NT + 255) / 256, b256, 0, stream>>>(tm, G, W_w, cWw, w2,
                                                       WTw, WTc, WT2, tot, NB);
    k_phist<<<NPB, b256, 0, stream>>>(dst, histT, ncols, cats, nvals, nm, tot,
                                      NB, NPB, CH, E, N);
    k_bscan<<<1, NBMAX, 0, stream>>>(tot, bbase, row_start, NB, N, E);
    k_boff<<<NB, NBMAX, 0, stream>>>(histT, bbase, boff, NPB);
    k_part<<<NPB, b256, 0, stream>>>(src, dst, boff, brec, NB, NPB, CH, E);
    k_csr<<<NB, b256, 0, stream>>>(brec, bbase, nm, G, row_start, se, sumt, N);

    // h1 = prelu(h @ W_w^T + W_b) ; fused s_u0/s_v0
    k_trans<true, true><<<nb32, b256, 0, stream>>>(
        h, WTw, W_b, pre_a, wh, s_u0, s_v0, A, N);

    // conv layer 0 fused: gather-agg(A) + transform + prelu + s_u1/s_v1 -> B
    k_aggt<true, true, false><<<nb16, b256, 0, stream>>>(
        A, se, row_start, sumt, s_u0, s_v0,
        WTc, cWb, pre_a, wh, s_u1, s_v1, nullptr, nullptr, nullptr, B, N);

    // conv layer 1 fused: gather-agg(B) + transform -> raw + emb_h (WF-overlay epilogue)
    k_aggt<false, false, true><<<nb16, b256, 0, stream>>>(
        B, se, row_start, sumt, s_u1, s_v1,
        WTc, cWb, pre_a, nullptr, nullptr, nullptr, WT2, b2, emb_out, rawOut, N);

    // post stage (A,B free now -> cur0, cur1)
    k_post1<<<nb32, b256, 0, stream>>>(rawOut, icols, ivals, psiW, psib, cats, tm, tsl,
                                       A, B, N);
    k_post2<<<nb32, b256, 0, stream>>>(A, B, ncols, nvals, w0, b0, w1, b1, emb_out, N);
}

// Round 14
// 317.091 us; speedup vs baseline: 1.0127x; 1.0127x over previous
//
#include <hip/hip_runtime.h>

constexpr int H  = 64;
constexpr int NT = 512;
constexpr int NBMAX = 512;   // max buckets (N<=131072)

#define FMA4(acc_, s_, v_) { (acc_).x += (s_)*(v_).x; (acc_).y += (s_)*(v_).y; \
                             (acc_).z += (s_)*(v_).z; (acc_).w += (s_)*(v_).w; }

// ---------------- Gram matrix of taxo_mean (+ fused weight transposes) --------------
__global__ void k_gram(const float* __restrict__ tm, float* __restrict__ G,
                       const float* __restrict__ Ww, const float* __restrict__ Wc,
                       const float* __restrict__ w2,
                       float* __restrict__ WTw, float* __restrict__ WTc,
                       float* __restrict__ WT2) {
    int idx = blockIdx.x * blockDim.x + threadIdx.x;
    if (idx < 64 * 64) {              // one-time transposes (first 16 blocks)
        int j = idx >> 6, l = idx & 63;
        WTw[l * 64 + j] = Ww[idx];
        WTc[l * 64 + j] = Wc[idx];
        if (j < 32) WT2[l * 32 + j] = w2[idx & 2047];
    }
    if (idx >= NT * NT) return;
    int a = idx >> 9, b = idx & (NT - 1);
    const float* ra = tm + a * H;
    const float* rb = tm + b * H;
    float s = 0.f;
#pragma unroll
    for (int k = 0; k < H; ++k) s += ra[k] * rb[k];
    G[idx] = s;
}

// ---------------- atomic-free radix partition by dst>>8 (+ fused nm build) ---------
__global__ void k_phist(const int* __restrict__ dst, int* __restrict__ histT,
                        const int* __restrict__ ncols, const int* __restrict__ cats,
                        const float* __restrict__ nvals, uint2* __restrict__ nm,
                        int NB, int NPB, int CH, int E, int N) {
    __shared__ int hist[NBMAX];
    int b = blockIdx.x, t = threadIdx.x;
    int gid = b * 256 + t;          // NPB*256 >= N
    if (gid < N) {
        int j = ncols[gid];
        nm[gid] = make_uint2(__float_as_uint(nvals[gid]),
                             (unsigned)(cats[j * 2] | (cats[j * 2 + 1] << 16)));
    }
    for (int i = t; i < NB; i += 256) hist[i] = 0;
    __syncthreads();
    int e0 = b * CH, e1 = min(E, e0 + CH);
    for (int e = e0 + t; e < e1; e += 256)
        atomicAdd(&hist[dst[e] >> 8], 1);
    __syncthreads();
    for (int i = t; i < NB; i += 256) histT[i * NPB + b] = hist[i];
}

// parallel bucket totals: one block per bucket, 256-thread row reduction
__global__ void k_btot(const int* __restrict__ histT, int* __restrict__ tot, int NPB) {
    __shared__ int sh[256];
    int bk = blockIdx.x, t = threadIdx.x;
    int s = 0;
    for (int j = t; j < NPB; j += 256) s += histT[bk * NPB + j];
    sh[t] = s;
    __syncthreads();
    for (int o = 128; o; o >>= 1) { if (t < o) sh[t] += sh[t + o]; __syncthreads(); }
    if (!t) tot[bk] = sh[0];
}

__global__ void k_bscan(const int* __restrict__ tot, int* __restrict__ bbase,
                        int* __restrict__ row_start, int NB, int N, int E) {
    __shared__ int sh[NBMAX];
    int t = threadIdx.x;
    int v = (t < NB) ? tot[t] : 0;
    sh[t] = v;
    __syncthreads();
    for (int o = 1; o < NBMAX; o <<= 1) {
        int x = (t >= o) ? sh[t - o] : 0;
        __syncthreads();
        sh[t] += x;
        __syncthreads();
    }
    if (t < NB) bbase[t] = sh[t] - v;
    if (t == 0) { bbase[NB] = E; row_start[N] = E; }
}

__global__ void k_boff(const int* __restrict__ histT, const int* __restrict__ bbase,
                       int* __restrict__ boff, int NPB) {
    __shared__ int sh[NBMAX];
    int bk = blockIdx.x, t = threadIdx.x;
    int v = (t < NPB) ? histT[bk * NPB + t] : 0;
    sh[t] = v;
    __syncthreads();
    for (int o = 1; o < NBMAX; o <<= 1) {
        int x = (t >= o) ? sh[t - o] : 0;
        __syncthreads();
        sh[t] += x;
        __syncthreads();
    }
    if (t < NPB) boff[bk * NPB + t] = bbase[bk] + sh[t] - v;
}

// packed record: src (24 bits) | (dst&255)<<24  — N < 2^24
__global__ void k_part(const int* __restrict__ src, const int* __restrict__ dst,
                       const int* __restrict__ boff, unsigned* __restrict__ brec,
                       int NB, int NPB, int CH, int E) {
    __shared__ int cur[NBMAX];
    int b = blockIdx.x, t = threadIdx.x;
    for (int i = t; i < NB; i += 256) cur[i] = boff[i * NPB + b];
    __syncthreads();
    int e0 = b * CH, e1 = min(E, e0 + CH);
    for (int e = e0 + t; e < e1; e += 256) {
        int s = src[e], d = dst[e];
        int pos = atomicAdd(&cur[d >> 8], 1);
        brec[pos] = (unsigned)s | ((unsigned)(d & 255) << 24);
    }
}

// one block per bucket: LDS degree count -> scan -> row_start; CSR window fill;
// fused wt (Gram trick) -> packed se = {src, exp(wt)}, LDS sumt.
__global__ void k_csr(const unsigned* __restrict__ brec, const int* __restrict__ bbase,
                      const uint2* __restrict__ nm, const float* __restrict__ G,
                      int* __restrict__ row_start, uint2* __restrict__ se,
                      float* __restrict__ sumt, int N) {
    __shared__ int   sdeg[256];
    __shared__ int   scur[256];
    __shared__ float ssum[256];
    __shared__ float snv[256];
    __shared__ int   scc[256];
    int b = blockIdx.x, t = threadIdx.x;
    int node0 = b << 8;
    int ebase = bbase[b], eend = bbase[b + 1];
    sdeg[t] = 0; scur[t] = 0; ssum[t] = 0.f;
    int n = node0 + t;
    if (n < N) { uint2 m = nm[n]; snv[t] = __uint_as_float(m.x); scc[t] = (int)m.y; }
    __syncthreads();
    for (int i = ebase + t; i < eend; i += 256)
        atomicAdd(&sdeg[brec[i] >> 24], 1);
    __syncthreads();
    int val = sdeg[t];
    for (int o = 1; o < 256; o <<= 1) {
        int x = (t >= o) ? sdeg[t - o] : 0;
        __syncthreads();
        sdeg[t] += x;
        __syncthreads();
    }
    int gstart = ebase + sdeg[t] - val;
    if (n < N) row_start[n] = gstart;
    sdeg[t] = gstart;
    __syncthreads();
    for (int i = ebase + t; i < eend; i += 256) {
        unsigned r = brec[i];
        int s = (int)(r & 0xFFFFFFu);
        int j = (int)(r >> 24);
        int c = atomicAdd(&scur[j], 1);
        int k = sdeg[j] + c;
        uint2 ms = nm[s];
        float nvs = __uint_as_float(ms.x);
        int cs = (int)ms.y;
        int cd = scc[j];
        float wt = nvs * snv[j] *
                   (G[(cs & 0xffff) * NT + (cd & 0xffff)] + G[(cs >> 16) * NT + (cd >> 16)]);
        float ev = __expf(wt);
        se[k] = make_uint2((unsigned)s, __float_as_uint(ev));
        atomicAdd(&ssum[j], ev);
    }
    __syncthreads();
    if (n < N) sumt[n] = ssum[t];
}

// ---------------- FUSED gather-aggregate + 64x64 transform ------------------------
// One 16-lane group per node. Phase 1: owner-lane gather with packed se (1x8B load).
// Phase 2: z staged to xs with XOR swizzle -> 0 conflicts (verified r8); WF staged
// linearly from pre-transposed WT. LDS = 20480 B -> 8 blocks/CU for BOTH layers.
// EMBH: after phase 2, WF is dead -> overlay W2S into WF (8KB linear copy) behind a
// barrier; epilogue = 16 lanes x 2 cols from swizzled xs (conflict-free, r8-verified).
#define LDH(S) (*reinterpret_cast<const float4*>(h_in + (size_t)(S) * H + f))
template <bool PRELU, bool SUV, bool EMBH>
__global__ void __launch_bounds__(256, 8)
k_aggt(const float* __restrict__ h_in, const uint2* __restrict__ se,
       const int* __restrict__ row_start,
       const float* __restrict__ sumt, const float* __restrict__ s_u,
       const float* __restrict__ s_v,
       const float* __restrict__ WT, const float* __restrict__ b,
       const float* __restrict__ a_ptr, const float* __restrict__ wh,
       float* __restrict__ s_u_o, float* __restrict__ s_v_o,
       const float* __restrict__ WT2, const float* __restrict__ b2,
       float* __restrict__ emb_out,
       float* __restrict__ out, int N) {
    __shared__ float WF[64 * 64];     // phase2: W^T ; EMBH epilogue: overlaid w2^T
    __shared__ float xs[4][256];      // per-wave, XOR-swizzled
    int t = threadIdx.x;
    for (int i = t; i < 64 * 64; i += 256) WF[i] = WT[i];
    __syncthreads();                  // no divergent exit before barriers (n<N predicated)
    int sg = t >> 4, l16 = t & 15, f = l16 * 4;
    int wid = t >> 6, g = sg & 3;
    int gsw = g << 2;                 // XOR swizzle key (word units)
    int n = blockIdx.x * 16 + sg;

    // ---- phase 1: gather-aggregate (owner-lane loop, packed se) ----
    float4 z = make_float4(0.f, 0.f, 0.f, 0.f);
    if (n < N) {
        int kb = row_start[n], ke = row_start[n + 1];
        if (ke > kb) {
            float sv = s_v[n];
            float invt = 0.5f / sumt[n];
            float ssf = 0.f;
            float4 zf0 = z, zf1 = z, zt0 = z, zt1 = z;
            for (int k0 = kb; k0 < ke; k0 += 16) {
                int cnt = ke - k0; cnt = cnt < 16 ? cnt : 16;
                int cl = cnt - 1;
                int myk = k0 + (l16 <= cl ? l16 : cl);
                uint2 p = se[myk];
                int ms = (int)p.x;
                float me = __uint_as_float(p.y) * invt;
                float mw = s_u[ms] + sv;
                mw = mw >= 0.f ? mw : 0.01f * mw;
                float mf = __expf(mw);
                if (l16 > cl) { mf = 0.f; me = 0.f; }
                ssf += mf;
                for (int j0 = 0; j0 < cnt; j0 += 4) {
                    int jB = min(j0 + 1, cl), jC = min(j0 + 2, cl), jD = min(j0 + 3, cl);
                    int sA = __shfl(ms, j0, 16), sB = __shfl(ms, jB, 16);
                    int sC = __shfl(ms, jC, 16), sD = __shfl(ms, jD, 16);
                    float tfA = __shfl(mf, j0, 16), tfB = __shfl(mf, jB, 16);
                    float tfC = __shfl(mf, jC, 16), tfD = __shfl(mf, jD, 16);
                    float teA = __shfl(me, j0, 16), teB = __shfl(me, jB, 16);
                    float teC = __shfl(me, jC, 16), teD = __shfl(me, jD, 16);
                    float fB = (j0 + 1 <= cl) ? tfB : 0.f;
                    float fC = (j0 + 2 <= cl) ? tfC : 0.f;
                    float fD = (j0 + 3 <= cl) ? tfD : 0.f;
                    float eB = (j0 + 1 <= cl) ? teB : 0.f;
                    float eC = (j0 + 2 <= cl) ? teC : 0.f;
                    float eD = (j0 + 3 <= cl) ? teD : 0.f;
                    const float4 hA = LDH(sA);
                    const float4 hB = LDH(sB);
                    const float4 hC = LDH(sC);
                    const float4 hD = LDH(sD);
                    FMA4(zf0, tfA, hA); FMA4(zt0, teA, hA);
                    FMA4(zf1, fB, hB);  FMA4(zt1, eB, hB);
                    FMA4(zf0, fC, hC);  FMA4(zt0, eC, hC);
                    FMA4(zf1, fD, hD);  FMA4(zt1, eD, hD);
                }
            }
            ssf += __shfl_xor(ssf, 1); ssf += __shfl_xor(ssf, 2);
            ssf += __shfl_xor(ssf, 4); ssf += __shfl_xor(ssf, 8);
            float invf = 0.5f / ssf;
            z.x = (zf0.x + zf1.x) * invf + (zt0.x + zt1.x);
            z.y = (zf0.y + zf1.y) * invf + (zt0.y + zt1.y);
            z.z = (zf0.z + zf1.z) * invf + (zt0.z + zt1.z);
            z.w = (zf0.w + zf1.w) * invf + (zt0.w + zt1.w);
        }
    }

    // ---- phase 2: transform via swizzled xs + WF GEMV ----
    *reinterpret_cast<float4*>(&xs[wid][(g << 6) | (f ^ gsw)]) = z;
    float a = PRELU ? a_ptr[0] : 0.f;
    float4 acc = *reinterpret_cast<const float4*>(b + f);
#pragma unroll 2
    for (int l0 = 0; l0 < 64; l0 += 4) {
        const float* wp = &WF[l0 * 64 + f];
        float4 wv0 = *reinterpret_cast<const float4*>(wp);
        float4 wv1 = *reinterpret_cast<const float4*>(wp + 64);
        float4 wv2 = *reinterpret_cast<const float4*>(wp + 128);
        float4 wv3 = *reinterpret_cast<const float4*>(wp + 192);
        float4 x4 = *reinterpret_cast<const float4*>(&xs[wid][(g << 6) | (l0 ^ gsw)]);
        FMA4(acc, x4.x, wv0); FMA4(acc, x4.y, wv1);
        FMA4(acc, x4.z, wv2); FMA4(acc, x4.w, wv3);
    }
    if constexpr (PRELU) {
        acc.x = acc.x >= 0.f ? acc.x : a * acc.x;
        acc.y = acc.y >= 0.f ? acc.y : a * acc.y;
        acc.z = acc.z >= 0.f ? acc.z : a * acc.z;
        acc.w = acc.w >= 0.f ? acc.w : a * acc.w;
    }
    if (n < N) *reinterpret_cast<float4*>(out + (size_t)n * H + f) = acc;
    if constexpr (SUV) {
        float4 wu = *reinterpret_cast<const float4*>(wh + f);
        float4 wv = *reinterpret_cast<const float4*>(wh + H + f);
        float u = acc.x * wu.x + acc.y * wu.y + acc.z * wu.z + acc.w * wu.w;
        float v = acc.x * wv.x + acc.y * wv.y + acc.z * wv.z + acc.w * wv.w;
        u += __shfl_xor(u, 1); v += __shfl_xor(v, 1);
        u += __shfl_xor(u, 2); v += __shfl_xor(v, 2);
        u += __shfl_xor(u, 4); v += __shfl_xor(v, 4);
        u += __shfl_xor(u, 8); v += __shfl_xor(v, 8);
        if (l16 == 0 && n < N) { s_u_o[n] = u; s_v_o[n] = v; }
    }
    if constexpr (EMBH) {
        // acc row into this wave's xs slot (wave-local: own reads completed above)
        *reinterpret_cast<float4*>(&xs[wid][(g << 6) | (f ^ gsw)]) = acc;
        __syncthreads();                     // all waves done reading WF
        for (int i = t; i < 64 * 32; i += 256) WF[i] = WT2[i];   // overlay w2^T
        __syncthreads();
        int c0 = 2 * l16;
        float2 bb2 = *reinterpret_cast<const float2*>(b2 + c0);
        float e0 = bb2.x, e1 = bb2.y;
#pragma unroll 2
        for (int l0 = 0; l0 < 64; l0 += 4) {
            float4 x4 = *reinterpret_cast<const float4*>(&xs[wid][(g << 6) | (l0 ^ gsw)]);
            const float* wp = &WF[l0 * 32 + c0];
            float2 w0v = *reinterpret_cast<const float2*>(wp);
            float2 w1v = *reinterpret_cast<const float2*>(wp + 32);
            float2 w2v = *reinterpret_cast<const float2*>(wp + 64);
            float2 w3v = *reinterpret_cast<const float2*>(wp + 96);
            e0 += x4.x * w0v.x + x4.y * w1v.x + x4.z * w2v.x + x4.w * w3v.x;
            e1 += x4.x * w0v.y + x4.y * w1v.y + x4.z * w2v.y + x4.w * w3v.y;
        }
        float sq = e0 * e0 + e1 * e1;
        sq += __shfl_xor(sq, 1);
        sq += __shfl_xor(sq, 2);
        sq += __shfl_xor(sq, 4);
        sq += __shfl_xor(sq, 8);
        float invn = 1.f / fmaxf(sqrtf(sq), 1e-12f);
        if (n < N) {
            *reinterpret_cast<float2*>(emb_out + (size_t)n * 96 + c0) =
                make_float2(e0 * invn, e1 * invn);
        }
    }
}

// ---------------- register-tiled 64x64 transform, 8 nodes per wave (layer 0) --------
template <bool PRELU, bool SUV>
__global__ void __launch_bounds__(256, 4)
k_trans(const float* __restrict__ in, const float* __restrict__ WT,
        const float* __restrict__ b, const float* __restrict__ a_ptr,
        const float* __restrict__ wh,
        float* __restrict__ s_u_o, float* __restrict__ s_v_o,
        float* __restrict__ out, int N) {
    __shared__ float WF[64 * 64];     // WF[l*64+j] = W[j][l]
    __shared__ float xs[4][8][68];    // [wave][node-slot][l]
    int t = threadIdx.x;
    for (int i = t; i < 64 * 64; i += 256) WF[i] = WT[i];
    __syncthreads();
    int wid = t >> 6, lane = t & 63;
    int g = lane >> 4, f = lane & 15;
    float a = PRELU ? a_ptr[0] : 0.f;
    float4 bias = *reinterpret_cast<const float4*>(b + 4 * f);
    int n0 = blockIdx.x * 32 + wid * 8 + g;
    int n1 = n0 + 4;
    float4 xv0 = make_float4(0.f, 0.f, 0.f, 0.f), xv1 = xv0;
    if (n0 < N) xv0 = *reinterpret_cast<const float4*>(in + (size_t)n0 * H + 4 * f);
    if (n1 < N) xv1 = *reinterpret_cast<const float4*>(in + (size_t)n1 * H + 4 * f);
    *reinterpret_cast<float4*>(&xs[wid][g][4 * f])     = xv0;
    *reinterpret_cast<float4*>(&xs[wid][4 + g][4 * f]) = xv1;
    float4 accP = make_float4(0.f, 0.f, 0.f, 0.f), accQ = accP;
#pragma unroll 2
    for (int l0 = 0; l0 < 64; l0 += 4) {
        const float* wp = &WF[l0 * 64 + 4 * f];
        float4 wv0 = *reinterpret_cast<const float4*>(wp);
        float4 wv1 = *reinterpret_cast<const float4*>(wp + 64);
        float4 wv2 = *reinterpret_cast<const float4*>(wp + 128);
        float4 wv3 = *reinterpret_cast<const float4*>(wp + 192);
        float4 xP = *reinterpret_cast<const float4*>(&xs[wid][g][l0]);
        float4 xQ = *reinterpret_cast<const float4*>(&xs[wid][4 + g][l0]);
        FMA4(accP, xP.x, wv0); FMA4(accP, xP.y, wv1);
        FMA4(accP, xP.z, wv2); FMA4(accP, xP.w, wv3);
        FMA4(accQ, xQ.x, wv0); FMA4(accQ, xQ.y, wv1);
        FMA4(accQ, xQ.z, wv2); FMA4(accQ, xQ.w, wv3);
    }
    auto epi = [&](float4 acc, int n) {
        acc.x += bias.x; acc.y += bias.y; acc.z += bias.z; acc.w += bias.w;
        if constexpr (PRELU) {
            acc.x = acc.x >= 0.f ? acc.x : a * acc.x;
            acc.y = acc.y >= 0.f ? acc.y : a * acc.y;
            acc.z = acc.z >= 0.f ? acc.z : a * acc.z;
            acc.w = acc.w >= 0.f ? acc.w : a * acc.w;
        }
        if (n < N) *reinterpret_cast<float4*>(out + (size_t)n * H + 4 * f) = acc;
        if constexpr (SUV) {
            float4 wu = *reinterpret_cast<const float4*>(wh + 4 * f);
            float4 wv = *reinterpret_cast<const float4*>(wh + H + 4 * f);
            float u = acc.x * wu.x + acc.y * wu.y + acc.z * wu.z + acc.w * wu.w;
            float v = acc.x * wv.x + acc.y * wv.y + acc.z * wv.z + acc.w * wv.w;
            u += __shfl_xor(u, 1); v += __shfl_xor(v, 1);
            u += __shfl_xor(u, 2); v += __shfl_xor(v, 2);
            u += __shfl_xor(u, 4); v += __shfl_xor(v, 4);
            u += __shfl_xor(u, 8); v += __shfl_xor(v, 8);
            if (f == 0 && n < N) { s_u_o[n] = u; s_v_o[n] = v; }
        }
    };
    epi(accP, n0);
    epi(accQ, n1);
}

// ---------------- post stage 1: hrev gather + Psi GEMV + both cur_i, 8 nodes/wave ----
__global__ void __launch_bounds__(256, 4)
k_post1(const float* __restrict__ raw, const int* __restrict__ icols,
        const float* __restrict__ ivals, const float* __restrict__ Psi,
        const float* __restrict__ psib, const int* __restrict__ cats,
        const float* __restrict__ tm, const float* __restrict__ tsl,
        float* __restrict__ cur0, float* __restrict__ cur1, int N) {
    __shared__ float PF[64 * 68];     // PF[l*68+j] = Psi[l][j]
    __shared__ float xs[4][8][68];
    int t = threadIdx.x;
    for (int i = t; i < 64 * 64; i += 256) { int l = i >> 6, j = i & 63; PF[l * 68 + j] = Psi[i]; }
    __syncthreads();
    int wid = t >> 6, lane = t & 63;
    int g = lane >> 4, f = lane & 15;
    float pb = psib[0];
    int n0 = blockIdx.x * 32 + wid * 8 + g;
    int n1 = n0 + 4;
    float4 hr0 = make_float4(0.f, 0.f, 0.f, 0.f), hr1 = hr0;
    if (n0 < N) {
        int c = icols[n0]; float iv = ivals[n0];
        float4 rv = *reinterpret_cast<const float4*>(raw + (size_t)c * H + 4 * f);
        hr0.x = iv * rv.x; hr0.y = iv * rv.y; hr0.z = iv * rv.z; hr0.w = iv * rv.w;
    }
    if (n1 < N) {
        int c = icols[n1]; float iv = ivals[n1];
        float4 rv = *reinterpret_cast<const float4*>(raw + (size_t)c * H + 4 * f);
        hr1.x = iv * rv.x; hr1.y = iv * rv.y; hr1.z = iv * rv.z; hr1.w = iv * rv.w;
    }
    *reinterpret_cast<float4*>(&xs[wid][g][4 * f])     = hr0;
    *reinterpret_cast<float4*>(&xs[wid][4 + g][4 * f]) = hr1;
    float4 v0 = make_float4(0.f, 0.f, 0.f, 0.f), v1 = v0;
#pragma unroll 2
    for (int l0 = 0; l0 < 64; l0 += 4) {
        const float* pp = &PF[l0 * 68 + 4 * f];
        float4 pv0 = *reinterpret_cast<const float4*>(pp);
        float4 pv1 = *reinterpret_cast<const float4*>(pp + 68);
        float4 pv2 = *reinterpret_cast<const float4*>(pp + 136);
        float4 pv3 = *reinterpret_cast<const float4*>(pp + 204);
        float4 xP = *reinterpret_cast<const float4*>(&xs[wid][g][l0]);
        float4 xQ = *reinterpret_cast<const float4*>(&xs[wid][4 + g][l0]);
        FMA4(v0, xP.x, pv0); FMA4(v0, xP.y, pv1); FMA4(v0, xP.z, pv2); FMA4(v0, xP.w, pv3);
        FMA4(v1, xQ.x, pv0); FMA4(v1, xQ.y, pv1); FMA4(v1, xQ.z, pv2); FMA4(v1, xQ.w, pv3);
    }
    auto epi = [&](float4 v, float4 hr, int n) {
        if (n >= N) return;
#pragma unroll
        for (int i2 = 0; i2 < 2; ++i2) {
            int c = cats[n * 2 + i2];
            float4 m4 = *reinterpret_cast<const float4*>(tm + (size_t)c * H + 4 * f);
            float sd = v.x * m4.x + v.y * m4.y + v.z * m4.z + v.w * m4.w;
            sd += __shfl_xor(sd, 1);
            sd += __shfl_xor(sd, 2);
            sd += __shfl_xor(sd, 4);
            sd += __shfl_xor(sd, 8);
            float sig = 1.f / (1.f + __expf(-(sd + pb)));
            float4 t4 = *reinterpret_cast<const float4*>(tsl + (size_t)c * H + 4 * f);
            float4 tau, cv;
            tau.x = sig * __expf(-__expf(t4.x));
            tau.y = sig * __expf(-__expf(t4.y));
            tau.z = sig * __expf(-__expf(t4.z));
            tau.w = sig * __expf(-__expf(t4.w));
            cv.x = (1.f - tau.x) * hr.x + tau.x * m4.x;
            cv.y = (1.f - tau.y) * hr.y + tau.y * m4.y;
            cv.z = (1.f - tau.z) * hr.z + tau.z * m4.z;
            cv.w = (1.f - tau.w) * hr.w + tau.w * m4.w;
            *reinterpret_cast<float4*>((i2 ? cur1 : cur0) + (size_t)n * H + 4 * f) = cv;
        }
    };
    epi(v0, hr0, n0);
    epi(v1, hr1, n1);
}

// ---------------- post stage 2: gather cur rows, combined 64-col GEMV, normalize --------
__global__ void __launch_bounds__(256, 4)
k_post2(const float* __restrict__ cur0, const float* __restrict__ cur1,
        const int* __restrict__ ncols, const float* __restrict__ nvals,
        const float* __restrict__ w0, const float* __restrict__ b0,
        const float* __restrict__ w1, const float* __restrict__ b1,
        float* __restrict__ emb_out, int N) {
    __shared__ float WC[64 * 68];     // cols 0..31: w0^T, 32..63: w1^T
    __shared__ float xs[4][4][2][68];
    int t = threadIdx.x;
    for (int i = t; i < 64 * 64; i += 256) {
        int j = i >> 6, l = i & 63;
        WC[l * 68 + j] = (j < 32) ? w0[j * 64 + l] : w1[(j - 32) * 64 + l];
    }
    __syncthreads();
    int wid = t >> 6, lane = t & 63;
    int g = lane >> 4, f = lane & 15;
    int half = f >> 3;
    const float* bb = half ? b1 : b0;
    float4 bias = *reinterpret_cast<const float4*>(bb + 4 * (f & 7));
    for (int it = 0; it < 2; ++it) {
        int n = blockIdx.x * 32 + wid * 8 + it * 4 + g;
        float4 x0 = make_float4(0.f, 0.f, 0.f, 0.f), x1 = x0;
        if (n < N) {
            int c = ncols[n];
            float gsc = nvals[n];
            float4 c0v = *reinterpret_cast<const float4*>(cur0 + (size_t)c * H + 4 * f);
            float4 c1v = *reinterpret_cast<const float4*>(cur1 + (size_t)c * H + 4 * f);
            x0.x = gsc * c0v.x; x0.y = gsc * c0v.y; x0.z = gsc * c0v.z; x0.w = gsc * c0v.w;
            x1.x = gsc * c1v.x; x1.y = gsc * c1v.y; x1.z = gsc * c1v.z; x1.w = gsc * c1v.w;
        }
        *reinterpret_cast<float4*>(&xs[wid][g][0][4 * f]) = x0;
        *reinterpret_cast<float4*>(&xs[wid][g][1][4 * f]) = x1;
        float4 acc = bias;
#pragma unroll 4
        for (int l0 = 0; l0 < 64; l0 += 4) {
            float4 x4  = *reinterpret_cast<const float4*>(&xs[wid][g][half][l0]);
            float4 wv0 = *reinterpret_cast<const float4*>(&WC[(l0 + 0) * 68 + 4 * f]);
            float4 wv1 = *reinterpret_cast<const float4*>(&WC[(l0 + 1) * 68 + 4 * f]);
            float4 wv2 = *reinterpret_cast<const float4*>(&WC[(l0 + 2) * 68 + 4 * f]);
            float4 wv3 = *reinterpret_cast<const float4*>(&WC[(l0 + 3) * 68 + 4 * f]);
            FMA4(acc, x4.x, wv0); FMA4(acc, x4.y, wv1);
            FMA4(acc, x4.z, wv2); FMA4(acc, x4.w, wv3);
        }
        float sq = acc.x * acc.x + acc.y * acc.y + acc.z * acc.z + acc.w * acc.w;
        sq += __shfl_xor(sq, 1);
        sq += __shfl_xor(sq, 2);
        sq += __shfl_xor(sq, 4);
        float invn = 1.f / fmaxf(sqrtf(sq), 1e-12f);
        if (n < N) {
            int jb = (f & 7) * 4;
            float* o = emb_out + (size_t)n * 96 + 32 + half;
            o[2 * (jb + 0)] = acc.x * invn;
            o[2 * (jb + 1)] = acc.y * invn;
            o[2 * (jb + 2)] = acc.z * invn;
            o[2 * (jb + 3)] = acc.w * invn;
        }
    }
}

extern "C" void kernel_launch(void* const* d_in, const int* in_sizes, int n_in,
                              void* d_out, int out_size, void* d_ws, size_t ws_size,
                              hipStream_t stream) {
    const float* h      = (const float*)d_in[0];
    const int*   src    = (const int*)d_in[1];
    const int*   dst    = (const int*)d_in[2];
    const int*   cats   = (const int*)d_in[3];
    const int*   icols  = (const int*)d_in[5];
    const float* ivals  = (const float*)d_in[6];
    const int*   ncols  = (const int*)d_in[8];
    const float* nvals  = (const float*)d_in[9];
    const float* W_w    = (const float*)d_in[10];
    const float* W_b    = (const float*)d_in[11];
    const float* pre_a  = (const float*)d_in[12];
    const float* tm     = (const float*)d_in[13];
    const float* tsl    = (const float*)d_in[14];
    const float* wh     = (const float*)d_in[15];
    const float* cWw    = (const float*)d_in[16];
    const float* cWb    = (const float*)d_in[17];
    const float* psiW   = (const float*)d_in[18];
    const float* psib   = (const float*)d_in[19];
    const float* w0     = (const float*)d_in[20];
    const float* b0     = (const float*)d_in[21];
    const float* w1     = (const float*)d_in[22];
    const float* b1     = (const float*)d_in[23];
    const float* w2     = (const float*)d_in[24];
    const float* b2     = (const float*)d_in[25];

    const int N = in_sizes[0] / H;   // 100000
    const int E = in_sizes[1];       // 1600000
    const int NB = (N + 255) >> 8;   // 391 buckets
    const int NPB = NB;
    const int CH = (E + NPB - 1) / NPB;

    char* ws = (char*)d_ws;
    size_t off = 0;
    auto alloc = [&](size_t bytes) -> void* {
        void* p = ws + off;
        off = (off + bytes + 255) & ~(size_t)255;
        return p;
    };
    float*    A        = (float*)   alloc((size_t)N * H * 4);   // h1; later cur0
    float*    B        = (float*)   alloc((size_t)N * H * 4);   // h2; later cur1
    uint2*    se       = (uint2*)   alloc((size_t)E * 8);       // packed {src, et}
    unsigned* brec     = (unsigned*)alloc((size_t)E * 4);
    uint2*    nm       = (uint2*)   alloc((size_t)N * 8);
    int*      row_start= (int*)     alloc((size_t)(N + 1) * 4);
    float*    sumt     = (float*)   alloc((size_t)N * 4);
    float*    s_u0     = (float*)   alloc((size_t)N * 4);
    float*    s_v0     = (float*)   alloc((size_t)N * 4);
    float*    s_u1     = (float*)   alloc((size_t)N * 4);
    float*    s_v1     = (float*)   alloc((size_t)N * 4);
    float*    G        = (float*)   alloc((size_t)NT * NT * 4);
    int*      histT    = (int*)     alloc((size_t)NB * NPB * 4);
    int*      boff     = (int*)     alloc((size_t)NB * NPB * 4);
    int*      tot      = (int*)     alloc((size_t)NB * 4);
    int*      bbase    = (int*)     alloc((size_t)(NB + 1) * 4);
    float*    WTw      = (float*)   alloc(64 * 64 * 4);
    float*    WTc      = (float*)   alloc(64 * 64 * 4);
    float*    WT2      = (float*)   alloc(64 * 32 * 4);
    (void)ws_size; (void)n_in; (void)out_size;

    float* rawOut  = (float*)d_out;                     // N*H
    float* emb_out = (float*)d_out + (size_t)N * H;     // N*96

    dim3 b256(256);
    int nb16 = (N + 15) / 16;
    int nb32 = (N + 31) / 32;

    k_gram<<<(NT * NT + 255) / 256, b256, 0, stream>>>(tm, G, W_w, cWw, w2,
                                                       WTw, WTc, WT2);
    k_phist<<<NPB, b256, 0, stream>>>(dst, histT, ncols, cats, nvals, nm,
                                      NB, NPB, CH, E, N);
    k_btot<<<NB, b256, 0, stream>>>(histT, tot, NPB);
    k_bscan<<<1, NBMAX, 0, stream>>>(tot, bbase, row_start, NB, N, E);
    k_boff<<<NB, NBMAX, 0, stream>>>(histT, bbase, boff, NPB);
    k_part<<<NPB, b256, 0, stream>>>(src, dst, boff, brec, NB, NPB, CH, E);
    k_csr<<<NB, b256, 0, stream>>>(brec, bbase, nm, G, row_start, se, sumt, N);

    // h1 = prelu(h @ W_w^T + W_b) ; fused s_u0/s_v0
    k_trans<true, true><<<nb32, b256, 0, stream>>>(
        h, WTw, W_b, pre_a, wh, s_u0, s_v0, A, N);

    // conv layer 0 fused: gather-agg(A) + transform + prelu + s_u1/s_v1 -> B
    k_aggt<true, true, false><<<nb16, b256, 0, stream>>>(
        A, se, row_start, sumt, s_u0, s_v0,
        WTc, cWb, pre_a, wh, s_u1, s_v1, nullptr, nullptr, nullptr, B, N);

    // conv layer 1 fused: gather-agg(B) + transform -> raw + emb_h (WF-overlay epilogue)
    k_aggt<false, false, true><<<nb16, b256, 0, stream>>>(
        B, se, row_start, sumt, s_u1, s_v1,
        WTc, cWb, pre_a, nullptr, nullptr, nullptr, WT2, b2, emb_out, rawOut, N);

    // post stage (A,B free now -> cur0, cur1)
    k_post1<<<nb32, b256, 0, stream>>>(rawOut, icols, ivals, psiW, psib, cats, tm, tsl,
                                       A, B, N);
    k_post2<<<nb32, b256, 0, stream>>>(A, B, ncols, nvals, w0, b0, w1, b1, emb_out, N);
}